// Round 11
// baseline (369.102 us; speedup 1.0000x reference)
//
#include <hip/hip_runtime.h>

// Problem constants
#define T_LEN 120
#define H 128
#define FC1_STRIDE 15360 // T*H

// workspace layout (bytes)
#define OFF_WHH   0u        // [512][128] bf16, pre-scaled by gate constant
#define OFF_WXB   131072u   // [512][32]  bf16 (W_ih cols 0-3, bias col 4), pre-scaled
#define OFF_FC1W  163840u   // [128][15360] bf16 (rows >=100 zero)
#define OFF_FC1B  4096000u  // [128] f32 (zero-padded)

typedef short short8 __attribute__((ext_vector_type(8)));   // 8 bf16 in 4 VGPRs
typedef float f32x4 __attribute__((ext_vector_type(4)));
typedef float f32x2 __attribute__((ext_vector_type(2)));    // packed-f32 pair (v_pk_*)
typedef unsigned int ui32x4 __attribute__((ext_vector_type(4)));

#define L2E 1.4426950408889634f
#define SWZ(r) (((((r) & 7) ^ (((r) >> 3) << 1))) << 4)
#define MFMA __builtin_amdgcn_mfma_f32_16x16x32_bf16

__device__ __forceinline__ unsigned short f2bu(float f) {   // f32 -> bf16 (RNE)
  unsigned u = __builtin_bit_cast(unsigned, f);
  u += 0x7fffu + ((u >> 16) & 1u);
  return (unsigned short)(u >> 16);
}
__device__ __forceinline__ unsigned cvt_pk_bf16(float lo, float hi) { // 2xf32 -> packed bf16 (RNE)
  unsigned r;
  asm("v_cvt_pk_bf16_f32 %0, %1, %2" : "=v"(r) : "v"(lo), "v"(hi));
  return r;
}
__device__ __forceinline__ float gate_scale(int row) {
  // rows 0-127: i, 128-255: f, 256-383: g, 384-511: o
  return ((row >> 7) == 2) ? 2.0f * L2E : -L2E;
}

// ---- one-time weight conversion (single launch) ----
__global__ void prep_all(const float* __restrict__ W_ih, const float* __restrict__ W_hh,
                         const float* __restrict__ b_ih, const float* __restrict__ b_hh,
                         const float* __restrict__ fc1_w, const float* __restrict__ fc1_b,
                         unsigned char* __restrict__ ws) {
  if (blockIdx.x < 1024) {
    unsigned short* w = (unsigned short*)(ws + OFF_FC1W);
    int j = blockIdx.x >> 3;
    int c0 = ((blockIdx.x & 7) * 256 + threadIdx.x) * 8;
    if (c0 >= FC1_STRIDE) return;
    short8 v = {0, 0, 0, 0, 0, 0, 0, 0};
    if (j < 100) {
      const float* src = fc1_w + j * FC1_STRIDE + c0;
#pragma unroll
      for (int e = 0; e < 8; ++e) ((unsigned short*)&v)[e] = f2bu(src[e]);
    }
    *(short8*)(w + j * FC1_STRIDE + c0) = v;
  } else {
    unsigned short* whh = (unsigned short*)(ws + OFF_WHH);
    unsigned short* wxb = (unsigned short*)(ws + OFF_WXB);
    float* fb = (float*)(ws + OFF_FC1B);
    int tid = (blockIdx.x - 1024) * 256 + threadIdx.x;
    const int nt = 8 * 256;
    for (int i = tid; i < 512 * 128; i += nt) {
      int row = i >> 7;
      whh[i] = f2bu(W_hh[i] * gate_scale(row));
    }
    for (int i = tid; i < 512 * 32; i += nt) {
      int j = i >> 5, k = i & 31;
      float s = gate_scale(j);
      float v = 0.f;
      if (k < 4) v = W_ih[j * 4 + k] * s;
      else if (k == 4) v = (b_ih[j] + b_hh[j]) * s;
      wxb[i] = f2bu(v);
    }
    for (int i = tid; i < 128; i += nt) fb[i] = (i < 100) ? fc1_b[i] : 0.f;
  }
}

// ---- fused persistent kernel: 512 blocks x 256 threads (4 waves), 2 blocks/CU ----
// 8 real batch rows per block mapped to M=16 tile rows {lq*4+q, q<2}.
// Wave w owns gate columns [32w,32w+32): for each gate, 2 col-tiles (bhh = 128 VGPR).
// fc1 is batched: h_t kept in an 8-deep LDS ring; every 8 steps each wave streams
// the fc1_w slices and accumulates. Two independent blocks per CU decorrelate
// barrier phases so one block's MFMA/VMEM fills the other's trans/latency stalls.
__global__ __launch_bounds__(256, 2)
void lstm_fused(const float* __restrict__ x, const float* __restrict__ h0,
                const float* __restrict__ c0, const float* __restrict__ fc2_w,
                const float* __restrict__ fc2_b, const unsigned char* __restrict__ ws,
                float* __restrict__ out) {
  __shared__ __align__(16) unsigned char xab[T_LEN * 128];   // [t][8 rows][16B bf16 frag]; reused as hid[8][132] f32
  __shared__ __align__(16) unsigned char hring[8 * 4096];    // 8-slot ring of bf16 h (16 tile rows x 256B, swizzled)
  __shared__ __align__(16) float fc2w_s[1000];
  __shared__ float fc2b_s[10];
  __shared__ float logit_s[8 * 12];

  const int tid = threadIdx.x;
  const int w = tid >> 6;        // wave 0..3
  const int l = tid & 63;
  const int lq = l >> 4;
  const int lc = l & 15;
  const int r0 = blockIdx.x * 8;

  const unsigned short* Whh = (const unsigned short*)(ws + OFF_WHH);
  const unsigned short* Wxb = (const unsigned short*)(ws + OFF_WXB);
  const unsigned short* FC1 = (const unsigned short*)(ws + OFF_FC1W);
  const float* FC1B = (const float*)(ws + OFF_FC1B);

  // stage fc2 weights
  for (int i = tid; i < 1000; i += 256) fc2w_s[i] = fc2_w[i];
  if (tid < 10) fc2b_s[tid] = fc2_b[tid];

  // pack x A-frags: [t][8 rows][16B] = {x0,x1,x2,x3,1.0,0,0,0} bf16
  for (int i = tid; i < 8 * T_LEN; i += 256) {
    int j = i / T_LEN, t = i - j * T_LEN;
    f32x4 xv = *(const f32x4*)(x + (r0 + j) * (T_LEN * 4) + t * 4);
    unsigned w0 = cvt_pk_bf16(xv[0], xv[1]);
    unsigned w1 = cvt_pk_bf16(xv[2], xv[3]);
    ui32x4 pk = {w0, w1, 0x3f80u, 0u};
    *(ui32x4*)(xab + t * 128 + j * 16) = pk;
  }
  // zero dummy tile rows ((r&3)>=2) of ALL 8 ring slots (never written by the loop)
  for (int i = tid; i < 4096; i += 256) {
    int slot = i >> 9;
    int rem = i & 511;
    int dr = rem >> 6;
    int word = rem & 63;
    int tr = ((dr >> 1) << 2) + 2 + (dr & 1);   // rows {2,3,6,7,10,11,14,15}
    *(unsigned*)(hring + slot * 4096 + tr * 256 + word * 4) = 0u;
  }
  // stage h0 -> ring slot 7 (step t=0 reads slot 7, writes slot 0)
  for (int i = tid; i < 512; i += 256) {
    int e = i * 2;
    int j = e >> 7, c = e & 127;
    int tr = ((j >> 1) << 2) + (j & 1);
    const float* hp = h0 + (r0 + j) * H + c;
    unsigned u = (unsigned)f2bu(hp[0]) | ((unsigned)f2bu(hp[1]) << 16);
    *(unsigned*)(hring + 7 * 4096 + tr * 256 + ((2 * c) ^ SWZ(tr))) = u;
  }
  // c0: lane owns real rows lq*2+q (q<2), cols {32w+lc, 32w+16+lc}
  float c_reg[2][2];
#pragma unroll
  for (int c = 0; c < 2; ++c)
#pragma unroll
    for (int q = 0; q < 2; ++q)
      c_reg[c][q] = c0[(r0 + lq * 2 + q) * H + w * 32 + c * 16 + lc];

  // register-resident B fragments: 4 gates x 2 col-tiles
  short8 bhh[4][2][4], bxb[4][2];
#pragma unroll
  for (int g = 0; g < 4; ++g)
#pragma unroll
    for (int c = 0; c < 2; ++c) {
      int n0 = g * 128 + w * 32 + c * 16;
#pragma unroll
      for (int kk = 0; kk < 4; ++kk)
        bhh[g][c][kk] = *(const short8*)(Whh + (n0 + lc) * H + kk * 32 + lq * 8);
      bxb[g][c] = *(const short8*)(Wxb + (n0 + lc) * 32 + lq * 8);
    }
  f32x4 facc0 = {0.f, 0.f, 0.f, 0.f}, facc1 = {0.f, 0.f, 0.f, 0.f};

  // swizzled h-store byte offsets [c][q] (tile row lq*4+q)
  unsigned soff[2][2];
#pragma unroll
  for (int c = 0; c < 2; ++c)
#pragma unroll
    for (int q = 0; q < 2; ++q) {
      int r = lq * 4 + q;
      int col = w * 32 + c * 16 + lc;
      soff[c][q] = (unsigned)(r * 256 + ((2 * col) ^ SWZ(r)));
    }

  const int jr = ((lc >> 2) << 1) | (lc & 1);   // A-tile row lc -> real batch row (dummies alias)

  __syncthreads();

  // initial A fragments from slot 7 (h0) + xa(t=0)
  short8 ha[4];
#pragma unroll
  for (int kk = 0; kk < 4; ++kk)
    ha[kk] = *(const short8*)(hring + 7 * 4096 + lc * 256 + ((kk * 64 + lq * 16) ^ SWZ(lc)));
  short8 xa = *(const short8*)(xab + jr * 16);

  const f32x4 zero4 = {0.f, 0.f, 0.f, 0.f};
  const f32x2 one2 = {1.f, 1.f};

  for (int t = 0; t < T_LEN; ++t) {
    unsigned char* hw = hring + ((t & 7) << 12);

    __builtin_amdgcn_s_setprio(1);
    // gate chains: 8 independent (4 gates x 2 tiles), depth 5 (xa head + 4 ha)
    f32x4 a00 = MFMA(xa, bxb[0][0], zero4, 0, 0, 0);
    f32x4 a01 = MFMA(xa, bxb[1][0], zero4, 0, 0, 0);
    f32x4 a02 = MFMA(xa, bxb[2][0], zero4, 0, 0, 0);
    f32x4 a03 = MFMA(xa, bxb[3][0], zero4, 0, 0, 0);
    f32x4 a10 = MFMA(xa, bxb[0][1], zero4, 0, 0, 0);
    f32x4 a11 = MFMA(xa, bxb[1][1], zero4, 0, 0, 0);
    f32x4 a12 = MFMA(xa, bxb[2][1], zero4, 0, 0, 0);
    f32x4 a13 = MFMA(xa, bxb[3][1], zero4, 0, 0, 0);
#pragma unroll
    for (int kk = 0; kk < 4; ++kk) {
      a00 = MFMA(ha[kk], bhh[0][0][kk], a00, 0, 0, 0);
      a01 = MFMA(ha[kk], bhh[1][0][kk], a01, 0, 0, 0);
      a02 = MFMA(ha[kk], bhh[2][0][kk], a02, 0, 0, 0);
      a03 = MFMA(ha[kk], bhh[3][0][kk], a03, 0, 0, 0);
      a10 = MFMA(ha[kk], bhh[0][1][kk], a10, 0, 0, 0);
      a11 = MFMA(ha[kk], bhh[1][1][kk], a11, 0, 0, 0);
      a12 = MFMA(ha[kk], bhh[2][1][kk], a12, 0, 0, 0);
      a13 = MFMA(ha[kk], bhh[3][1][kk], a13, 0, 0, 0);
    }

    // next xa (independent LDS broadcast read)
    int tn = (t + 1 < T_LEN) ? t + 1 : t;
    short8 xan = *(const short8*)(xab + tn * 128 + jr * 16);

    // activations per col-tile (q-pair rcp batching, packed-f32 pair math)
#pragma unroll
    for (int c = 0; c < 2; ++c) {
      f32x4 gi = c ? a10 : a00;
      f32x4 gf = c ? a11 : a01;
      f32x4 gg = c ? a12 : a02;
      f32x4 go = c ? a13 : a03;
      f32x2 ea = {__builtin_amdgcn_exp2f(gi[0]), __builtin_amdgcn_exp2f(gi[1])};
      f32x2 eb = {__builtin_amdgcn_exp2f(gf[0]), __builtin_amdgcn_exp2f(gf[1])};
      f32x2 ec = {__builtin_amdgcn_exp2f(gg[0]), __builtin_amdgcn_exp2f(gg[1])};
      f32x2 ed = {__builtin_amdgcn_exp2f(go[0]), __builtin_amdgcn_exp2f(go[1])};
      f32x2 a = ea + one2, b = eb + one2, d = ec + one2, e = ed + one2;
      f32x2 ab = a * b, de = d * e;
      float rAB = __builtin_amdgcn_rcpf(ab[0] * ab[1]);
      float rDE = __builtin_amdgcn_rcpf(de[0] * de[1]);
      f32x2 rab = {rAB * ab[1], rAB * ab[0]};
      f32x2 rde = {rDE * de[1], rDE * de[0]};
      f32x2 iv = b * rab, fv = a * rab;
      f32x2 erde = e * rde;
      f32x2 gv = one2 - (erde + erde);
      f32x2 ov = d * rde;
      f32x2 cp = {c_reg[c][0], c_reg[c][1]};
      f32x2 cn = fv * cp + iv * gv;
      c_reg[c][0] = cn[0]; c_reg[c][1] = cn[1];
      f32x2 cs = cn * 2.8853900817779268f;
      f32x2 et = {__builtin_amdgcn_exp2f(cs[0]), __builtin_amdgcn_exp2f(cs[1])};
      f32x2 tt = et + one2;
      float rT = __builtin_amdgcn_rcpf(tt[0] * tt[1]);
      float hv0 = ov[0] * (1.f - 2.f * (rT * tt[1]));
      float hv1 = ov[1] * (1.f - 2.f * (rT * tt[0]));
      unsigned pk = cvt_pk_bf16(hv0, hv1);
      *(unsigned short*)(hw + soff[c][0]) = (unsigned short)pk;
      *(unsigned short*)(hw + soff[c][1]) = (unsigned short)(pk >> 16);
    }
    __builtin_amdgcn_s_setprio(0);

    asm volatile("s_waitcnt lgkmcnt(0)" ::: "memory");
    __builtin_amdgcn_s_barrier();
    asm volatile("" ::: "memory");

    // h_t fragments for next step's gates
#pragma unroll
    for (int kk = 0; kk < 4; ++kk)
      ha[kk] = *(const short8*)(hw + lc * 256 + ((kk * 64 + lq * 16) ^ SWZ(lc)));
    xa = xan;

    // fc1 phase every 8 steps: stream fc1_w slices, consume ring slots 0..7
    if ((t & 7) == 7) {
      int tb = t - 7;
      const unsigned short* f0base = FC1 + (w * 32 + lc) * FC1_STRIDE + lq * 8;
      const unsigned short* f1base = FC1 + (w * 32 + 16 + lc) * FC1_STRIDE + lq * 8;
#pragma unroll 2
      for (int s = 0; s < 8; ++s) {
        const unsigned short* f0 = f0base + (tb + s) * 128;
        const unsigned short* f1 = f1base + (tb + s) * 128;
        short8 fb0[4], fb1[4], hs[4];
#pragma unroll
        for (int kk = 0; kk < 4; ++kk) {
          fb0[kk] = *(const short8*)(f0 + kk * 32);
          fb1[kk] = *(const short8*)(f1 + kk * 32);
          hs[kk] = *(const short8*)(hring + s * 4096 + lc * 256 + ((kk * 64 + lq * 16) ^ SWZ(lc)));
        }
#pragma unroll
        for (int kk = 0; kk < 4; ++kk) {
          facc0 = MFMA(hs[kk], fb0[kk], facc0, 0, 0, 0);
          facc1 = MFMA(hs[kk], fb1[kk], facc1, 0, 0, 0);
        }
      }
      // ring slots are all about to be overwritten by the next 8 steps
      asm volatile("s_waitcnt lgkmcnt(0)" ::: "memory");
      __builtin_amdgcn_s_barrier();
      asm volatile("" ::: "memory");
    }
  }

  // ---- epilogue: bias+ReLU -> fc2 -> log_softmax (8 rows) ----
  float bias0 = FC1B[w * 32 + lc];
  float bias1 = FC1B[w * 32 + 16 + lc];
  __syncthreads();                 // xab free for reuse as hid
  float* hid = (float*)xab;        // [8][132] padded
#pragma unroll
  for (int q = 0; q < 2; ++q) {
    float v0 = facc0[q] + bias0;
    float v1 = facc1[q] + bias1;
    hid[(lq * 2 + q) * 132 + w * 32 + lc] = v0 > 0.f ? v0 : 0.f;
    hid[(lq * 2 + q) * 132 + w * 32 + 16 + lc] = v1 > 0.f ? v1 : 0.f;
  }
  __syncthreads();
  if (tid < 80) {
    int r = tid & 7, k = tid >> 3;
    float a = fc2b_s[k];
#pragma unroll 4
    for (int j = 0; j < 100; ++j) a += hid[r * 132 + j] * fc2w_s[k * 100 + j];
    logit_s[r * 12 + k] = a;
  }
  __syncthreads();
  if (tid < 8) {
    int r = tid;
    float m = logit_s[r * 12];
#pragma unroll
    for (int k = 1; k < 10; ++k) m = fmaxf(m, logit_s[r * 12 + k]);
    float s = 0.f;
#pragma unroll
    for (int k = 0; k < 10; ++k)
      s += __builtin_amdgcn_exp2f(L2E * (logit_s[r * 12 + k] - m));
    float ls = __builtin_amdgcn_logf(s) * 0.6931471805599453f;
#pragma unroll
    for (int k = 0; k < 10; ++k)
      out[(r0 + r) * 10 + k] = logit_s[r * 12 + k] - m - ls;
  }
}

extern "C" void kernel_launch(void* const* d_in, const int* in_sizes, int n_in,
                              void* d_out, int out_size, void* d_ws, size_t ws_size,
                              hipStream_t stream) {
  const float* x     = (const float*)d_in[0];
  const float* h0    = (const float*)d_in[1];
  const float* c0    = (const float*)d_in[2];
  const float* W_ih  = (const float*)d_in[3];
  const float* W_hh  = (const float*)d_in[4];
  const float* b_ih  = (const float*)d_in[5];
  const float* b_hh  = (const float*)d_in[6];
  const float* fc1_w = (const float*)d_in[7];
  const float* fc1_b = (const float*)d_in[8];
  const float* fc2_w = (const float*)d_in[9];
  const float* fc2_b = (const float*)d_in[10];
  float* out = (float*)d_out;
  unsigned char* ws = (unsigned char*)d_ws;

  prep_all<<<1032, 256, 0, stream>>>(W_ih, W_hh, b_ih, b_hh, fc1_w, fc1_b, ws);
  lstm_fused<<<512, 256, 0, stream>>>(x, h0, c0, fc2_w, fc2_b, ws, out);
}

// Round 12
// 135.637 us; speedup vs baseline: 2.7212x; 2.7212x over previous
//
#include <hip/hip_runtime.h>

// Problem constants
#define T_LEN 120
#define H 128
#define ROWS 16          // batch rows per block
#define FC1_STRIDE 15360 // T*H

// workspace layout (bytes)
#define OFF_WHH   0u        // [512][128] bf16, pre-scaled by gate constant
#define OFF_WXB   131072u   // [512][32]  bf16 (W_ih cols 0-3, bias col 4), pre-scaled
#define OFF_FC1W  163840u   // [128][15360] bf16 (rows >=100 zero)
#define OFF_FC1B  4096000u  // [128] f32 (zero-padded)

typedef short short8 __attribute__((ext_vector_type(8)));   // 8 bf16 in 4 VGPRs
typedef float f32x4 __attribute__((ext_vector_type(4)));
typedef float f32x2 __attribute__((ext_vector_type(2)));    // packed-f32 pair (v_pk_*)
typedef unsigned int ui32x4 __attribute__((ext_vector_type(4)));

#define L2E 1.4426950408889634f
#define SWZ(r) (((((r) & 7) ^ (((r) >> 3) << 1))) << 4)
#define MFMA __builtin_amdgcn_mfma_f32_16x16x32_bf16

__device__ __forceinline__ unsigned short f2bu(float f) {   // f32 -> bf16 (RNE)
  unsigned u = __builtin_bit_cast(unsigned, f);
  u += 0x7fffu + ((u >> 16) & 1u);
  return (unsigned short)(u >> 16);
}
__device__ __forceinline__ unsigned cvt_pk_bf16(float lo, float hi) { // 2xf32 -> packed bf16 (RNE)
  unsigned r;
  asm("v_cvt_pk_bf16_f32 %0, %1, %2" : "=v"(r) : "v"(lo), "v"(hi));
  return r;
}
__device__ __forceinline__ float gate_scale(int row) {
  // rows 0-127: i, 128-255: f, 256-383: g, 384-511: o
  return ((row >> 7) == 2) ? 2.0f * L2E : -L2E;
}

// ---- one-time weight conversion (single launch) ----
__global__ void prep_all(const float* __restrict__ W_ih, const float* __restrict__ W_hh,
                         const float* __restrict__ b_ih, const float* __restrict__ b_hh,
                         const float* __restrict__ fc1_w, const float* __restrict__ fc1_b,
                         unsigned char* __restrict__ ws) {
  if (blockIdx.x < 1024) {
    unsigned short* w = (unsigned short*)(ws + OFF_FC1W);
    int j = blockIdx.x >> 3;
    int c0 = ((blockIdx.x & 7) * 256 + threadIdx.x) * 8;
    if (c0 >= FC1_STRIDE) return;
    short8 v = {0, 0, 0, 0, 0, 0, 0, 0};
    if (j < 100) {
      const float* src = fc1_w + j * FC1_STRIDE + c0;
#pragma unroll
      for (int e = 0; e < 8; ++e) ((unsigned short*)&v)[e] = f2bu(src[e]);
    }
    *(short8*)(w + j * FC1_STRIDE + c0) = v;
  } else {
    unsigned short* whh = (unsigned short*)(ws + OFF_WHH);
    unsigned short* wxb = (unsigned short*)(ws + OFF_WXB);
    float* fb = (float*)(ws + OFF_FC1B);
    int tid = (blockIdx.x - 1024) * 256 + threadIdx.x;
    const int nt = 8 * 256;
    for (int i = tid; i < 512 * 128; i += nt) {
      int row = i >> 7;
      whh[i] = f2bu(W_hh[i] * gate_scale(row));
    }
    for (int i = tid; i < 512 * 32; i += nt) {
      int j = i >> 5, k = i & 31;
      float s = gate_scale(j);
      float v = 0.f;
      if (k < 4) v = W_ih[j * 4 + k] * s;
      else if (k == 4) v = (b_ih[j] + b_hh[j]) * s;
      wxb[i] = f2bu(v);
    }
    for (int i = tid; i < 128; i += nt) fb[i] = (i < 100) ? fc1_b[i] : 0.f;
  }
}

// ---- fused persistent kernel: 256 blocks x 512 threads ----
__global__ __launch_bounds__(512, 2)
void lstm_fused(const float* __restrict__ x, const float* __restrict__ h0,
                const float* __restrict__ c0, const float* __restrict__ fc2_w,
                const float* __restrict__ fc2_b, const unsigned char* __restrict__ ws,
                float* __restrict__ out) {
  __shared__ __align__(16) unsigned char xab[T_LEN * 256];      // packed x A-frags; reused as hid[16][132] f32
  __shared__ __align__(16) unsigned char h_lds[2 * 4096];       // double-buffered bf16 h (16 rows x 256B, swizzled)
  __shared__ __align__(16) float fc2w_s[1000];
  __shared__ float fc2b_s[10];
  __shared__ float logit_s[ROWS * 12];

  const int tid = threadIdx.x;
  const int w = tid >> 6;
  const int l = tid & 63;
  const int lq = l >> 4;
  const int lc = l & 15;
  const int r0 = blockIdx.x * ROWS;
  const int hcol = w * 16 + lc;

  const unsigned short* Whh = (const unsigned short*)(ws + OFF_WHH);
  const unsigned short* Wxb = (const unsigned short*)(ws + OFF_WXB);
  const unsigned short* FC1 = (const unsigned short*)(ws + OFF_FC1W);
  const float* FC1B = (const float*)(ws + OFF_FC1B);

  // stage fc2 weights
  for (int i = tid; i < 1000; i += 512) fc2w_s[i] = fc2_w[i];
  if (tid < 10) fc2b_s[tid] = fc2_b[tid];

  // pre-pack x A-frags for all t: slot (t,row) = 16B {x0,x1,x2,x3,1.0,0,0,0} bf16
  for (int i = tid; i < ROWS * T_LEN; i += 512) {
    int rr = i / T_LEN, t = i - rr * T_LEN;
    f32x4 xv = *(const f32x4*)(x + (r0 + rr) * (T_LEN * 4) + t * 4);
    unsigned w0 = cvt_pk_bf16(xv[0], xv[1]);
    unsigned w1 = cvt_pk_bf16(xv[2], xv[3]);
    ui32x4 pk = {w0, w1, 0x3f80u, 0u};
    *(ui32x4*)(xab + t * 256 + rr * 16) = pk;
  }
  // stage h0 -> buffer 1 (loop t=0 writes buffer 0)
  for (int e = tid * 2; e < ROWS * H; e += 1024) {
    int r = e >> 7, c = e & 127;
    unsigned u = (unsigned)f2bu(h0[(r0 + r) * H + c]) |
                 ((unsigned)f2bu(h0[(r0 + r) * H + c + 1]) << 16);
    *(unsigned*)(h_lds + 4096 + r * 256 + ((2 * c) ^ SWZ(r))) = u;
  }
  // c0: lane owns rows lq*4+q, col hcol
  float c_reg[4];
#pragma unroll
  for (int q = 0; q < 4; ++q) c_reg[q] = c0[(r0 + lq * 4 + q) * H + hcol];

  // register-resident B fragments; wave w owns gate tiles {w, 8+w, 16+w, 24+w}
  short8 bhh[4][4], bxb[4];
#pragma unroll
  for (int g = 0; g < 4; ++g) {
    int n0 = (g * 8 + w) * 16;
#pragma unroll
    for (int kk = 0; kk < 4; ++kk)
      bhh[g][kk] = *(const short8*)(Whh + (n0 + lc) * H + kk * 32 + lq * 8);
    bxb[g] = *(const short8*)(Wxb + (n0 + lc) * 32 + lq * 8);
  }
  const unsigned short* fc1base = FC1 + (w * 16 + lc) * FC1_STRIDE + lq * 8;  // hoisted base
  f32x4 facc = {0.f, 0.f, 0.f, 0.f};

  // precomputed swizzled h-store byte offsets for q=0..3
  unsigned soff[4];
#pragma unroll
  for (int q = 0; q < 4; ++q) {
    int r = lq * 4 + q;
    soff[q] = (unsigned)(r * 256 + ((2 * hcol) ^ SWZ(r)));
  }

  __syncthreads();

  // initial A fragments (h0, buffer 1) + xa(t=0) + accX(t=0)
  short8 ha[4];
#pragma unroll
  for (int kk = 0; kk < 4; ++kk)
    ha[kk] = *(const short8*)(h_lds + 4096 + lc * 256 + ((kk * 64 + lq * 16) ^ SWZ(lc)));
  short8 xa = *(const short8*)(xab + lc * 16);

  const f32x4 zero4 = {0.f, 0.f, 0.f, 0.f};
  f32x4 accX0 = MFMA(xa, bxb[0], zero4, 0, 0, 0);
  f32x4 accX1 = MFMA(xa, bxb[1], zero4, 0, 0, 0);
  f32x4 accX2 = MFMA(xa, bxb[2], zero4, 0, 0, 0);
  f32x4 accX3 = MFMA(xa, bxb[3], zero4, 0, 0, 0);

  // fc1 B-frags held one step behind (zero for t=0: first pre-barrier fc1 MFMA adds 0)
  short8 fbh0 = {0,0,0,0,0,0,0,0}, fbh1 = {0,0,0,0,0,0,0,0};
  short8 fbh2 = {0,0,0,0,0,0,0,0}, fbh3 = {0,0,0,0,0,0,0,0};

  const f32x2 one2 = {1.f, 1.f};

#pragma unroll 4
  for (int t = 0; t < T_LEN; ++t) {
    // fb for slice t: issue VMEM first (independent; consumed next iteration)
    const unsigned short* fp = fc1base + t * 128;
    short8 nfb0 = *(const short8*)(fp + 0);
    short8 nfb1 = *(const short8*)(fp + 32);
    short8 nfb2 = *(const short8*)(fp + 64);
    short8 nfb3 = *(const short8*)(fp + 96);

    // --- critical section: gates (split chains, depth 3) + activations ---
    __builtin_amdgcn_s_setprio(1);
    f32x4 lo0 = accX0, lo1 = accX1, lo2 = accX2, lo3 = accX3;
    f32x4 hi0 = zero4, hi1 = zero4, hi2 = zero4, hi3 = zero4;
    lo0 = MFMA(ha[0], bhh[0][0], lo0, 0, 0, 0);
    lo1 = MFMA(ha[0], bhh[1][0], lo1, 0, 0, 0);
    lo2 = MFMA(ha[0], bhh[2][0], lo2, 0, 0, 0);
    lo3 = MFMA(ha[0], bhh[3][0], lo3, 0, 0, 0);
    hi0 = MFMA(ha[2], bhh[0][2], hi0, 0, 0, 0);
    hi1 = MFMA(ha[2], bhh[1][2], hi1, 0, 0, 0);
    hi2 = MFMA(ha[2], bhh[2][2], hi2, 0, 0, 0);
    hi3 = MFMA(ha[2], bhh[3][2], hi3, 0, 0, 0);
    lo0 = MFMA(ha[1], bhh[0][1], lo0, 0, 0, 0);
    lo1 = MFMA(ha[1], bhh[1][1], lo1, 0, 0, 0);
    lo2 = MFMA(ha[1], bhh[2][1], lo2, 0, 0, 0);
    lo3 = MFMA(ha[1], bhh[3][1], lo3, 0, 0, 0);
    hi0 = MFMA(ha[3], bhh[0][3], hi0, 0, 0, 0);
    hi1 = MFMA(ha[3], bhh[1][3], hi1, 0, 0, 0);
    hi2 = MFMA(ha[3], bhh[2][3], hi2, 0, 0, 0);
    hi3 = MFMA(ha[3], bhh[3][3], hi3, 0, 0, 0);

    // fc1 for slice t-1 with stale ha (= h_{t-1}): fills MFMA pipe during activations
    facc = MFMA(ha[0], fbh0, facc, 0, 0, 0);
    facc = MFMA(ha[1], fbh1, facc, 0, 0, 0);
    facc = MFMA(ha[2], fbh2, facc, 0, 0, 0);
    facc = MFMA(ha[3], fbh3, facc, 0, 0, 0);

    f32x4 acc0 = lo0 + hi0;
    f32x4 acc1 = lo1 + hi1;
    f32x4 acc2 = lo2 + hi2;
    f32x4 acc3 = lo3 + hi3;

    fbh0 = nfb0; fbh1 = nfb1; fbh2 = nfb2; fbh3 = nfb3;
    // next xa (LDS broadcast read; consumed post-barrier by accX)
    int tn = (t + 1 < T_LEN) ? t + 1 : t;
    short8 xan = *(const short8*)(xab + tn * 256 + lc * 16);

    // activations: q-pair rcp batching (26 trans/lane), packed-f32 pair math
    unsigned char* hw = h_lds + (t & 1) * 4096;
#pragma unroll
    for (int qp = 0; qp < 2; ++qp) {
      const int q0 = qp * 2, q1 = q0 + 1;
      f32x2 ea = {__builtin_amdgcn_exp2f(acc0[q0]), __builtin_amdgcn_exp2f(acc0[q1])};
      f32x2 eb = {__builtin_amdgcn_exp2f(acc1[q0]), __builtin_amdgcn_exp2f(acc1[q1])};
      f32x2 ec = {__builtin_amdgcn_exp2f(acc2[q0]), __builtin_amdgcn_exp2f(acc2[q1])};
      f32x2 ed = {__builtin_amdgcn_exp2f(acc3[q0]), __builtin_amdgcn_exp2f(acc3[q1])};
      f32x2 a = ea + one2, b = eb + one2, d = ec + one2, e = ed + one2;
      f32x2 ab = a * b, de = d * e;
      float rAB = __builtin_amdgcn_rcpf(ab[0] * ab[1]);
      float rDE = __builtin_amdgcn_rcpf(de[0] * de[1]);
      f32x2 rab = {rAB * ab[1], rAB * ab[0]};
      f32x2 rde = {rDE * de[1], rDE * de[0]};
      f32x2 iv = b * rab, fv = a * rab;
      f32x2 erde = e * rde;
      f32x2 gv = one2 - (erde + erde);
      f32x2 ov = d * rde;
      f32x2 cp = {c_reg[q0], c_reg[q1]};
      f32x2 cn = fv * cp + iv * gv;
      c_reg[q0] = cn[0]; c_reg[q1] = cn[1];
      f32x2 cs = cn * 2.8853900817779268f;
      f32x2 et = {__builtin_amdgcn_exp2f(cs[0]), __builtin_amdgcn_exp2f(cs[1])};
      f32x2 tt = et + one2;
      float rT = __builtin_amdgcn_rcpf(tt[0] * tt[1]);
      float hv0 = ov[0] * (1.f - 2.f * (rT * tt[1]));
      float hv1 = ov[1] * (1.f - 2.f * (rT * tt[0]));
      unsigned pk = cvt_pk_bf16(hv0, hv1);
      *(unsigned short*)(hw + soff[q0]) = (unsigned short)pk;
      *(unsigned short*)(hw + soff[q1]) = (unsigned short)(pk >> 16);
    }
    __builtin_amdgcn_s_setprio(0);

    // barrier immediately after stores: shortest possible arrival tail
    asm volatile("s_waitcnt lgkmcnt(0)" ::: "memory");
    __builtin_amdgcn_s_barrier();
    asm volatile("" ::: "memory");

    // post-barrier: issue ha reads, then accX MFMAs inside the read-latency shadow
#pragma unroll
    for (int kk = 0; kk < 4; ++kk)
      ha[kk] = *(const short8*)(hw + lc * 256 + ((kk * 64 + lq * 16) ^ SWZ(lc)));
    accX0 = MFMA(xan, bxb[0], zero4, 0, 0, 0);
    accX1 = MFMA(xan, bxb[1], zero4, 0, 0, 0);
    accX2 = MFMA(xan, bxb[2], zero4, 0, 0, 0);
    accX3 = MFMA(xan, bxb[3], zero4, 0, 0, 0);
  }
  // final fc1 term: F_119 with h_119 (ha holds h_119 after last barrier)
  facc = MFMA(ha[0], fbh0, facc, 0, 0, 0);
  facc = MFMA(ha[1], fbh1, facc, 0, 0, 0);
  facc = MFMA(ha[2], fbh2, facc, 0, 0, 0);
  facc = MFMA(ha[3], fbh3, facc, 0, 0, 0);

  // ---- epilogue: bias+ReLU -> fc2 -> log_softmax ----
  float bias = FC1B[hcol];
  __syncthreads();                 // everyone out of the loop; xab free
  float* hid = (float*)xab;        // [16][132] padded
#pragma unroll
  for (int q = 0; q < 4; ++q) {
    float v = facc[q] + bias;
    hid[(lq * 4 + q) * 132 + hcol] = v > 0.f ? v : 0.f;
  }
  __syncthreads();
  if (tid < 160) {
    int r = tid & 15, k = tid >> 4;
    float a = fc2b_s[k];
#pragma unroll 4
    for (int j = 0; j < 100; ++j) a += hid[r * 132 + j] * fc2w_s[k * 100 + j];
    logit_s[r * 12 + k] = a;
  }
  __syncthreads();
  if (tid < 16) {
    int r = tid;
    float m = logit_s[r * 12];
#pragma unroll
    for (int k = 1; k < 10; ++k) m = fmaxf(m, logit_s[r * 12 + k]);
    float s = 0.f;
#pragma unroll
    for (int k = 0; k < 10; ++k)
      s += __builtin_amdgcn_exp2f(L2E * (logit_s[r * 12 + k] - m));
    float ls = __builtin_amdgcn_logf(s) * 0.6931471805599453f;
#pragma unroll
    for (int k = 0; k < 10; ++k)
      out[(r0 + r) * 10 + k] = logit_s[r * 12 + k] - m - ls;
  }
}

extern "C" void kernel_launch(void* const* d_in, const int* in_sizes, int n_in,
                              void* d_out, int out_size, void* d_ws, size_t ws_size,
                              hipStream_t stream) {
  const float* x     = (const float*)d_in[0];
  const float* h0    = (const float*)d_in[1];
  const float* c0    = (const float*)d_in[2];
  const float* W_ih  = (const float*)d_in[3];
  const float* W_hh  = (const float*)d_in[4];
  const float* b_ih  = (const float*)d_in[5];
  const float* b_hh  = (const float*)d_in[6];
  const float* fc1_w = (const float*)d_in[7];
  const float* fc1_b = (const float*)d_in[8];
  const float* fc2_w = (const float*)d_in[9];
  const float* fc2_b = (const float*)d_in[10];
  float* out = (float*)d_out;
  unsigned char* ws = (unsigned char*)d_ws;

  prep_all<<<1032, 256, 0, stream>>>(W_ih, W_hh, b_ih, b_hh, fc1_w, fc1_b, ws);
  lstm_fused<<<256, 512, 0, stream>>>(x, h0, c0, fc2_w, fc2_b, ws, out);
}